// Round 4
// baseline (174.755 us; speedup 1.0000x reference)
//
#include <hip/hip_runtime.h>
#include <math.h>

// Problem constants (fixed by the reference setup_inputs): B=2, P=8192, K=16
#define PP    8192
#define NB    2
#define NPTS  16384          // NB * PP
#define KNN   16
#define EPSV  1e-17f
#define CH    128            // chunks of 64 sorted points per batch
#define NCELL 4096           // 12-bit Morton (4 bits/axis)
#define BIGU  0xFFFFFFFFu

// ---------------------------------------------------------------------------
// R4: transposed exact KNN. One WAVE owns one query at a time (lanes = 64
// candidates); skip decisions are per-query wave-uniform -> tight gates.
//  S1 memset hist | S2 morton hist | S3 scan | S4 scatter | S5 bboxes
//  K1 knn_t: per-query own-chunk bitonic seed + ascending-dmin2 chunk
//     extraction with exact skip + fused phi/n1 tail (sorted space)
//  K2 denoise2 (sorted space) | K3 loss (sorted space, dist recomputed) | K4 mean
// Exactness: chunks are extracted in ascending floor-packed dmin2; we stop
// when min remaining floor-pack(dmin2*0.999999) >= keys[15] (uint compare,
// positive-float order == uint order). Every candidate key in an unprocessed
// chunk is >= that floor; keys only shrink; keys injective (idx bits) -> no
// final-set member can be skipped. All selection loops run in the UINT
// domain so dmin2 == 0 (denormal bit patterns) cannot be flushed/merged.
// The scalar loss is permutation-invariant, so the whole pipeline stays in
// sorted space; perm is only used to gather normals.
// ---------------------------------------------------------------------------

__device__ __forceinline__ int spread3(int v) {   // 4-bit v -> bits 0,3,6,9
    return (v & 1) | ((v & 2) << 2) | ((v & 4) << 4) | ((v & 8) << 6);
}

__global__ void hist_kernel(const float* __restrict__ pts,
                            int* __restrict__ hist) {
    const int p = blockIdx.x * blockDim.x + threadIdx.x;   // 0..16383
    const float x = pts[p * 3 + 0];
    const float y = pts[p * 3 + 1];
    const float z = pts[p * 3 + 2];
    const int ix = (int)fminf(fmaxf((x + 5.0f) * 1.6f, 0.0f), 15.0f);
    const int iy = (int)fminf(fmaxf((y + 5.0f) * 1.6f, 0.0f), 15.0f);
    const int iz = (int)fminf(fmaxf((z + 5.0f) * 1.6f, 0.0f), 15.0f);
    const int c = spread3(ix) | (spread3(iy) << 1) | (spread3(iz) << 2);
    atomicAdd(&hist[(p >> 13) * NCELL + c], 1);
}

__global__ void scan_kernel(const int* __restrict__ hist,
                            int* __restrict__ cursor) {
    // one block per batch, 1024 threads, 4 bins/thread
    const int b = blockIdx.x;
    const int t = threadIdx.x;
    const int base = b * NCELL;
    const int v0 = hist[base + t * 4 + 0];
    const int v1 = hist[base + t * 4 + 1];
    const int v2 = hist[base + t * 4 + 2];
    const int v3 = hist[base + t * 4 + 3];
    const int s4 = v0 + v1 + v2 + v3;
    const int lane = t & 63, wid = t >> 6;
    int v = s4;
#pragma unroll
    for (int off = 1; off < 64; off <<= 1) {
        int u = __shfl_up(v, off, 64);
        if (lane >= off) v += u;
    }
    __shared__ int wtot[16];
    if (lane == 63) wtot[wid] = v;
    __syncthreads();
    if (wid == 0) {
        int w = (lane < 16) ? wtot[lane] : 0;
#pragma unroll
        for (int off = 1; off < 16; off <<= 1) {
            int u = __shfl_up(w, off, 64);
            if (lane >= off) w += u;
        }
        if (lane < 16) wtot[lane] = w;          // inclusive wave totals
    }
    __syncthreads();
    const int wbase = (wid > 0) ? wtot[wid - 1] : 0;
    const int excl = wbase + v - s4;            // exclusive prefix, this thread
    const int o0 = b * PP + excl;
    cursor[base + t * 4 + 0] = o0;
    cursor[base + t * 4 + 1] = o0 + v0;
    cursor[base + t * 4 + 2] = o0 + v0 + v1;
    cursor[base + t * 4 + 3] = o0 + v0 + v1 + v2;
}

__global__ void scatter_kernel(const float* __restrict__ pts,
                               int* __restrict__ cursor,
                               float4* __restrict__ sorted4,
                               int* __restrict__ perm) {
    const int p = blockIdx.x * blockDim.x + threadIdx.x;
    const float x = pts[p * 3 + 0];
    const float y = pts[p * 3 + 1];
    const float z = pts[p * 3 + 2];
    const int ix = (int)fminf(fmaxf((x + 5.0f) * 1.6f, 0.0f), 15.0f);
    const int iy = (int)fminf(fmaxf((y + 5.0f) * 1.6f, 0.0f), 15.0f);
    const int iz = (int)fminf(fmaxf((z + 5.0f) * 1.6f, 0.0f), 15.0f);
    const int c = spread3(ix) | (spread3(iy) << 1) | (spread3(iz) << 2);
    const int pos = atomicAdd(&cursor[(p >> 13) * NCELL + c], 1);
    sorted4[pos] = make_float4(x, y, z, x * x + y * y + z * z);
    perm[pos] = p & (PP - 1);
}

__global__ void bbox_kernel(const float4* __restrict__ sorted4,
                            float4* __restrict__ bbmin,
                            float4* __restrict__ bbmax) {
    const int lane = threadIdx.x & 63;
    const int wave = threadIdx.x >> 6;
    const int cw = blockIdx.x * 8 + wave;       // 0..255 (abs chunk)
    const float4 v = sorted4[cw * 64 + lane];
    float mnx = v.x, mny = v.y, mnz = v.z;
    float mxx = v.x, mxy = v.y, mxz = v.z;
#pragma unroll
    for (int off = 32; off >= 1; off >>= 1) {
        mnx = fminf(mnx, __shfl_xor(mnx, off, 64));
        mny = fminf(mny, __shfl_xor(mny, off, 64));
        mnz = fminf(mnz, __shfl_xor(mnz, off, 64));
        mxx = fmaxf(mxx, __shfl_xor(mxx, off, 64));
        mxy = fmaxf(mxy, __shfl_xor(mxy, off, 64));
        mxz = fmaxf(mxz, __shfl_xor(mxz, off, 64));
    }
    if (lane == 0) {
        bbmin[cw] = make_float4(mnx, mny, mnz, 0.f);
        bbmax[cw] = make_float4(mxx, mxy, mxz, 0.f);
    }
}

// wave-wide min of a uint, result in ALL lanes
__device__ __forceinline__ unsigned wmin64u(unsigned v) {
#pragma unroll
    for (int off = 32; off >= 1; off >>= 1) {
        const unsigned o = (unsigned)__shfl_xor((int)v, off, 64);
        v = (o < v) ? o : v;
    }
    return v;
}

// sorted-ascending insert of one value into a replicated 16-list
__device__ __forceinline__ void insert16(float (&keys)[KNN], float kk) {
#pragma unroll
    for (int s = KNN - 1; s >= 1; --s)
        keys[s] = __builtin_amdgcn_fmed3f(keys[s - 1], kk, keys[s]);
    keys[0] = fminf(keys[0], kk);
}

// ---- K1: transposed exact KNN + phi + first denoise (fused, sorted space) --
__global__ __launch_bounds__(256) void knn_t_kernel(
        const float4* __restrict__ sorted4,
        const int*    __restrict__ perm,
        const float*  __restrict__ normals,
        const float4* __restrict__ bbmin,
        const float4* __restrict__ bbmax,
        int*   __restrict__ out_idx,      // sorted-local neighbor idx
        float* __restrict__ out_phi,
        float* __restrict__ out_n1) {     // sorted-order rows
    const int lane = threadIdx.x & 63;
    const int W = blockIdx.x * 4 + (threadIdx.x >> 6);  // 0..4095
    const int b = W >> 11;                               // 2048 waves/batch
    const int q0l = W & 2047;
    const float4* sb = sorted4 + (size_t)b * PP;
    const float*  bn = normals + (size_t)b * PP * 3;
    const int pbase = b << 13;

    // hoist bboxes once per wave: lane -> chunks (lane, lane+64)
    const float4 mnA = bbmin[b * CH + lane];
    const float4 mxA = bbmax[b * CH + lane];
    const float4 mnB = bbmin[b * CH + lane + 64];
    const float4 mxB = bbmax[b * CH + lane + 64];

    for (int k = 0; k < 4; ++k) {                 // 4 stride-mixed queries
        const int qloc = q0l + k * 2048;          // local sorted index
        const float4 q4 = sb[qloc];               // broadcast load
        const float qx = q4.x, qy = q4.y, qz = q4.z;
        const float d2q = qx * qx + qy * qy + qz * qz;
        const int c0 = qloc >> 6;

        // ---- phase A: own chunk -> bitonic sort 64, replicate top-16 ------
        unsigned v;
        {
            const float4 c4 = sb[c0 * 64 + lane];
            const float dot = fmaf(qz, c4.z, fmaf(qy, c4.y, qx * c4.x));
            const float d  = fmaf(-2.0f, dot, d2q + c4.w);
            const float dc = fmaxf(d, 0.0f);
            const int j = c0 * 64 + lane;
            v = (__float_as_uint(dc) & 0xFFFFE000u) | (unsigned)j;
            if (j == qloc) v = BIGU;              // exclude self
        }
#pragma unroll
        for (int kk = 2; kk <= 64; kk <<= 1) {
#pragma unroll
            for (int jj = kk >> 1; jj >= 1; jj >>= 1) {
                const unsigned o = (unsigned)__shfl_xor((int)v, jj, 64);
                const bool up    = ((lane & kk) == 0);
                const bool lower = ((lane & jj) == 0);
                const unsigned mn = (v < o) ? v : o;
                const unsigned mx = (v < o) ? o : v;
                v = (lower == up) ? mn : mx;
            }
        }
        float keys[KNN];                          // replicated ascending 16
#pragma unroll
        for (int s = 0; s < KNN; ++s)
            keys[s] = __uint_as_float((unsigned)__shfl((int)v, s, 64));

        // ---- phase B: packed dmin2 to all chunks, ascending extraction ----
        unsigned dmA, dmB;
        {
            float ax = fmaxf(fmaxf(mnA.x - qx, qx - mxA.x), 0.0f);
            float ay = fmaxf(fmaxf(mnA.y - qy, qy - mxA.y), 0.0f);
            float az = fmaxf(fmaxf(mnA.z - qz, qz - mxA.z), 0.0f);
            const float da = (ax * ax + ay * ay + az * az) * 0.999999f;
            dmA = (__float_as_uint(da) & 0xFFFFE000u) | (unsigned)lane;
            if (lane == c0) dmA = BIGU;           // own chunk done
            float bx = fmaxf(fmaxf(mnB.x - qx, qx - mxB.x), 0.0f);
            float by = fmaxf(fmaxf(mnB.y - qy, qy - mxB.y), 0.0f);
            float bz = fmaxf(fmaxf(mnB.z - qz, qz - mxB.z), 0.0f);
            const float db = (bx * bx + by * by + bz * bz) * 0.999999f;
            dmB = (__float_as_uint(db) & 0xFFFFE000u) | (unsigned)(lane + 64);
            if (lane + 64 == c0) dmB = BIGU;
        }
        while (true) {
            const unsigned dmc = (dmA < dmB) ? dmA : dmB;
            const unsigned m = wmin64u(dmc);      // uniform across lanes
            const unsigned fl = m & 0xFFFFE000u;  // clear chunk-id bits
            if (fl >= __float_as_uint(keys[KNN - 1])) break;   // exact stop
            const int c = (int)(m & 0x1FFFu);     // chunk id from low bits
            if (dmA == m) dmA = BIGU;             // consume (unique)
            if (dmB == m) dmB = BIGU;
            // process chunk c (c != c0, so no self here)
            unsigned ck;
            {
                const float4 c4 = sb[c * 64 + lane];
                const float dot = fmaf(qz, c4.z, fmaf(qy, c4.y, qx * c4.x));
                const float d  = fmaf(-2.0f, dot, d2q + c4.w);
                const float dc = fmaxf(d, 0.0f);
                ck = (__float_as_uint(dc) & 0xFFFFE000u)
                   | (unsigned)(c * 64 + lane);
            }
            while (true) {                        // ascending merge, early out
                const unsigned cm = wmin64u(ck);
                if (cm >= __float_as_uint(keys[KNN - 1])) break;
                insert16(keys, __uint_as_float(cm));
                if (ck == cm) ck = BIGU;          // unique lane consumes
            }
        }

        // ---- phase C: fused tail (exact dists, phi, d1, n1) ---------------
        const int slot = lane & 15;               // groups 1-3 mirror group 0
        float myk = keys[0];
#pragma unroll
        for (int s = 1; s < KNN; ++s) myk = (slot == s) ? keys[s] : myk;
        const int j = (int)(__float_as_uint(myk) & 0x1FFFu);

        const float4 nb4 = sb[j];
        const float dot = fmaf(qz, nb4.z, fmaf(qy, nb4.y, qx * nb4.x));
        float dd = fmaf(-2.0f, dot, d2q + nb4.w);
        dd = fmaxf(dd, 0.0f);

        float d1 = dd;
#pragma unroll
        for (int off = 8; off >= 1; off >>= 1)
            d1 = fminf(d1, __shfl_xor(d1, off, 16));

        const float s0v  = d1 * 8.0f;             // 2 * FILTER_SCALE^2 = 8
        const float sden = (s0v < EPSV) ? EPSV : s0v;
        const float w  = fmaxf(1.0f - dd / sden, 0.0f);
        const float ph = (w * w) * (w * w);

        const int jo = perm[pbase + j];           // original idx (normals only)
        const float nx = bn[jo * 3 + 0];
        const float ny = bn[jo * 3 + 1];
        const float nz = bn[jo * 3 + 2];
        float sx = ph * nx, sy = ph * ny, sz = ph * nz, ss = ph;
#pragma unroll
        for (int off = 8; off >= 1; off >>= 1) {
            sx += __shfl_xor(sx, off, 16);
            sy += __shfl_xor(sy, off, 16);
            sz += __shfl_xor(sz, off, 16);
            ss += __shfl_xor(ss, off, 16);
        }

        const int qrow = pbase + qloc;            // sorted-order row
        if (lane < 16) {
            out_idx[qrow * KNN + slot] = j;
            out_phi[qrow * KNN + slot] = ph;
        }
        if (lane == 0) {
            const float den = (ss < EPSV) ? EPSV : ss;
            out_n1[qrow * 3 + 0] = sx / den;
            out_n1[qrow * 3 + 1] = sy / den;
            out_n1[qrow * 3 + 2] = sz / den;
        }
    }
}

// ---- K2: normal_w + second denoise (n2), sorted space -----------------------
__global__ void denoise2_kernel(const int* __restrict__ idx,
                                const float* __restrict__ phi,
                                const float* __restrict__ n1,
                                float* __restrict__ nw_out,
                                float* __restrict__ n2_out) {
    const int q = blockIdx.x * blockDim.x + threadIdx.x;
    if (q >= NPTS) return;
    const int b = q >> 13;
    const int gbase = b * PP;
    const float INV_SIG = 1.0f / (0.75f * 0.75f);

    const float ax = n1[q * 3 + 0];
    const float ay = n1[q * 3 + 1];
    const float az = n1[q * 3 + 2];
    const float an = fmaxf(sqrtf(ax * ax + ay * ay + az * az), 1e-12f);
    const float rx = ax / an, ry = ay / an, rz = az / an;

    float swn = 0.f, ox = 0.f, oy = 0.f, oz = 0.f;
#pragma unroll
    for (int s = 0; s < KNN; ++s) {
        const int j = idx[q * KNN + s];           // sorted-local
        const float bx = n1[(gbase + j) * 3 + 0];
        const float by = n1[(gbase + j) * 3 + 1];
        const float bz = n1[(gbase + j) * 3 + 2];
        const float bnn = fmaxf(sqrtf(bx * bx + by * by + bz * bz), 1e-12f);
        const float ux = bx / bnn - rx;
        const float uy = by / bnn - ry;
        const float uz = bz / bnn - rz;
        const float dq = ux * ux + uy * uy + uz * uz;
        const float nw = expf(-dq * INV_SIG);
        nw_out[q * KNN + s] = nw;
        const float wk = phi[q * KNN + s] * nw;
        ox += wk * bx;                 // raw n1 (unnormalized), per reference
        oy += wk * by;
        oz += wk * bz;
        swn += wk;
    }
    const float den = (swn < EPSV) ? EPSV : swn;
    n2_out[q * 3 + 0] = ox / den;
    n2_out[q * 3 + 1] = oy / den;
    n2_out[q * 3 + 2] = oz / den;
}

// ---- K3: weights_proj + point-to-plane loss (sorted space, dist recomputed) -
__global__ void loss_kernel(const float4* __restrict__ sorted4,
                            const int* __restrict__ idx,
                            const float* __restrict__ phi,
                            const float* __restrict__ nw,
                            const float* __restrict__ n2,
                            float* __restrict__ partial) {
    const int q = blockIdx.x * 64 + threadIdx.x;   // block = 64 (one wave)
    const int b = q >> 13;
    const int il = q & (PP - 1);
    const float4* sb = sorted4 + (size_t)b * PP;
    const int gbase = b * PP;

    const float4 p4 = sb[il];
    const float px = p4.x, py = p4.y, pz = p4.z;
    const float d2q = px * px + py * py + pz * pz; // same expr as knn_t

    int jn[KNN];
    float d[KNN];
#pragma unroll
    for (int s = 0; s < KNN; ++s) {
        jn[s] = idx[q * KNN + s];
        const float4 nb4 = sb[jn[s]];
        const float dot = fmaf(pz, nb4.z, fmaf(py, nb4.y, px * nb4.x));
        const float dv  = fmaf(-2.0f, dot, d2q + nb4.w);
        d[s] = fmaxf(dv, 0.0f);                   // bit-identical to knn_t
    }
    float d1 = d[0];
#pragma unroll
    for (int s = 1; s < KNN; ++s) d1 = fminf(d1, d[s]);
    const float thresh = 4.0f * d1;                // FILTER_SCALE * d1 * 2

    float num = 0.f, den = 0.f;
#pragma unroll
    for (int s = 0; s < KNN; ++s) {
        float w = phi[q * KNN + s] * nw[q * KNN + s];
        if (d[s] > thresh) w = 0.f;                // ball-query mask
        const int j = jn[s];
        const float4 nb4 = sb[j];
        const float nx = n2[(gbase + j) * 3 + 0];
        const float ny = n2[(gbase + j) * 3 + 1];
        const float nz = n2[(gbase + j) * 3 + 2];
        const float dts = (nb4.x - px) * nx +
                          (nb4.y - py) * ny +
                          (nb4.z - pz) * nz;
        num += dts * dts * w;
        den += w;
    }
    const float dd = (den < EPSV) ? EPSV : den;
    float loss = num / dd;

#pragma unroll
    for (int off = 32; off >= 1; off >>= 1) loss += __shfl_down(loss, off, 64);
    if (threadIdx.x == 0) partial[blockIdx.x] = loss;
}

// ---- K4: final mean ---------------------------------------------------------
__global__ void finalize_kernel(const float* __restrict__ partial,
                                float* __restrict__ out) {
    float v = partial[threadIdx.x] + partial[threadIdx.x + 64] +
              partial[threadIdx.x + 128] + partial[threadIdx.x + 192];
#pragma unroll
    for (int off = 32; off >= 1; off >>= 1) v += __shfl_down(v, off, 64);
    if (threadIdx.x == 0) out[0] = v / (float)NPTS;
}

// ---- launch -----------------------------------------------------------------
extern "C" void kernel_launch(void* const* d_in, const int* in_sizes, int n_in,
                              void* d_out, int out_size, void* d_ws, size_t ws_size,
                              hipStream_t stream) {
    const float* points  = (const float*)d_in[0];   // (2, 8192, 3) f32
    const float* normals = (const float*)d_in[1];   // (2, 8192, 3) f32
    float* out = (float*)d_out;                     // scalar f32

    // workspace layout (floats), total 950528 < proven 1147136 budget:
    //   idx   @ 0       (262144)
    //   phi   @ 262144  (262144)
    //   nw    @ 524288  (262144)  -- doubles as sort scratch (dead after knn)
    //   n1    @ 786432  (49152)
    //   n2    @ 835584  (49152)
    //   sorted4 @ 884736 (65536)  -- float4-aligned, live through loss
    //   part  @ 950272  (256)
    float* wsf    = (float*)d_ws;
    int*   w_idx  = (int*)wsf;
    float* w_phi  = wsf + 262144;
    float* w_nw   = wsf + 524288;
    float* w_n1   = wsf + 786432;
    float* w_n2   = wsf + 835584;
    float4* w_sorted4 = (float4*)(wsf + 884736);
    float* w_part = wsf + 950272;
    // sort scratch inside the nw region (dead once knn_t completes)
    int*    w_perm   = (int*)(wsf + 524288);        // 16384 ints
    int*    w_hist   = (int*)(wsf + 540672);        // 8192 ints
    int*    w_cursor = (int*)(wsf + 548864);        // 8192 ints
    float4* w_bbmin  = (float4*)(wsf + 557056);     // 1024 floats
    float4* w_bbmax  = (float4*)(wsf + 558080);     // 1024 floats

    hipMemsetAsync(w_hist, 0, NB * NCELL * sizeof(int), stream);
    hist_kernel   <<<NPTS / 256, 256, 0, stream>>>(points, w_hist);
    scan_kernel   <<<NB, 1024, 0, stream>>>(w_hist, w_cursor);
    scatter_kernel<<<NPTS / 256, 256, 0, stream>>>(points, w_cursor, w_sorted4, w_perm);
    bbox_kernel   <<<32, 512, 0, stream>>>(w_sorted4, w_bbmin, w_bbmax);
    knn_t_kernel  <<<1024, 256, 0, stream>>>(w_sorted4, w_perm, normals,
                                             w_bbmin, w_bbmax,
                                             w_idx, w_phi, w_n1);
    denoise2_kernel<<<NPTS / 256, 256, 0, stream>>>(w_idx, w_phi, w_n1, w_nw, w_n2);
    loss_kernel   <<<NPTS / 64, 64, 0, stream>>>(w_sorted4, w_idx, w_phi, w_nw, w_n2, w_part);
    finalize_kernel<<<1, 64, 0, stream>>>(w_part, out);
}

// Round 5
// 164.915 us; speedup vs baseline: 1.0597x; 1.0597x over previous
//
#include <hip/hip_runtime.h>
#include <math.h>

// Problem constants (fixed by the reference setup_inputs): B=2, P=8192, K=16
#define PP    8192
#define NB    2
#define NPTS  16384          // NB * PP
#define KNN   16
#define EPSV  1e-17f
#define CH    128            // chunks of 64 sorted points per batch
#define NCELL 4096           // 12-bit Morton (4 bits/axis)

#define KEY_BIG 3.0e38f      // > any real key, finite

// ---------------------------------------------------------------------------
// R5: 8-queries-per-wave exact KNN. Lane (i,u): query i (0..7), sub-lane u
// (0..7). Each lane keeps a PRIVATE top-16 (med3 insert chain, no cross-lane)
// over the disjoint candidate stream m = u + 8t of every processed chunk.
// Chunk gate: per-lane dmin2(MY query, chunk bbox), uint-packed floor;
// process iff __any(fl < keys[15]) over the 8-query union (tight).
// Exactness: skipped chunk => for every lane, every candidate key in it is
// >= fl >= keys[15](lane) >= lane's final keys[15] >= that query's merged
// 16th; keys injective (idx bits) => candidate provably not in final set.
// Own chunk is processed first unconditionally (keys start at KEY_BIG).
// Cross-lane only at the end: 3 bitonic merge16 stages across sub-lanes.
// Epilogue kernels are thread-per-(q,s) with 16-lane shuffle reductions.
// Pipeline stays in sorted space (loss is permutation-invariant); perm is
// used only to gather normals.
// ---------------------------------------------------------------------------

__device__ __forceinline__ int spread3(int v) {   // 4-bit v -> bits 0,3,6,9
    return (v & 1) | ((v & 2) << 2) | ((v & 4) << 4) | ((v & 8) << 6);
}

__global__ void hist_kernel(const float* __restrict__ pts,
                            int* __restrict__ hist) {
    const int p = blockIdx.x * blockDim.x + threadIdx.x;   // 0..16383
    const float x = pts[p * 3 + 0];
    const float y = pts[p * 3 + 1];
    const float z = pts[p * 3 + 2];
    const int ix = (int)fminf(fmaxf((x + 5.0f) * 1.6f, 0.0f), 15.0f);
    const int iy = (int)fminf(fmaxf((y + 5.0f) * 1.6f, 0.0f), 15.0f);
    const int iz = (int)fminf(fmaxf((z + 5.0f) * 1.6f, 0.0f), 15.0f);
    const int c = spread3(ix) | (spread3(iy) << 1) | (spread3(iz) << 2);
    atomicAdd(&hist[(p >> 13) * NCELL + c], 1);
}

__global__ void scan_kernel(const int* __restrict__ hist,
                            int* __restrict__ cursor) {
    // one block per batch, 1024 threads, 4 bins/thread
    const int b = blockIdx.x;
    const int t = threadIdx.x;
    const int base = b * NCELL;
    const int v0 = hist[base + t * 4 + 0];
    const int v1 = hist[base + t * 4 + 1];
    const int v2 = hist[base + t * 4 + 2];
    const int v3 = hist[base + t * 4 + 3];
    const int s4 = v0 + v1 + v2 + v3;
    const int lane = t & 63, wid = t >> 6;
    int v = s4;
#pragma unroll
    for (int off = 1; off < 64; off <<= 1) {
        int u = __shfl_up(v, off, 64);
        if (lane >= off) v += u;
    }
    __shared__ int wtot[16];
    if (lane == 63) wtot[wid] = v;
    __syncthreads();
    if (wid == 0) {
        int w = (lane < 16) ? wtot[lane] : 0;
#pragma unroll
        for (int off = 1; off < 16; off <<= 1) {
            int u = __shfl_up(w, off, 64);
            if (lane >= off) w += u;
        }
        if (lane < 16) wtot[lane] = w;          // inclusive wave totals
    }
    __syncthreads();
    const int wbase = (wid > 0) ? wtot[wid - 1] : 0;
    const int excl = wbase + v - s4;            // exclusive prefix, this thread
    const int o0 = b * PP + excl;
    cursor[base + t * 4 + 0] = o0;
    cursor[base + t * 4 + 1] = o0 + v0;
    cursor[base + t * 4 + 2] = o0 + v0 + v1;
    cursor[base + t * 4 + 3] = o0 + v0 + v1 + v2;
}

__global__ void scatter_kernel(const float* __restrict__ pts,
                               int* __restrict__ cursor,
                               float4* __restrict__ sorted4,
                               int* __restrict__ perm) {
    const int p = blockIdx.x * blockDim.x + threadIdx.x;
    const float x = pts[p * 3 + 0];
    const float y = pts[p * 3 + 1];
    const float z = pts[p * 3 + 2];
    const int ix = (int)fminf(fmaxf((x + 5.0f) * 1.6f, 0.0f), 15.0f);
    const int iy = (int)fminf(fmaxf((y + 5.0f) * 1.6f, 0.0f), 15.0f);
    const int iz = (int)fminf(fmaxf((z + 5.0f) * 1.6f, 0.0f), 15.0f);
    const int c = spread3(ix) | (spread3(iy) << 1) | (spread3(iz) << 2);
    const int pos = atomicAdd(&cursor[(p >> 13) * NCELL + c], 1);
    sorted4[pos] = make_float4(x, y, z, x * x + y * y + z * z);
    perm[pos] = p & (PP - 1);
}

__global__ void bbox_kernel(const float4* __restrict__ sorted4,
                            float4* __restrict__ bbmin,
                            float4* __restrict__ bbmax) {
    const int lane = threadIdx.x & 63;
    const int wave = threadIdx.x >> 6;
    const int cw = blockIdx.x * 8 + wave;       // 0..255 (abs chunk)
    const float4 v = sorted4[cw * 64 + lane];
    float mnx = v.x, mny = v.y, mnz = v.z;
    float mxx = v.x, mxy = v.y, mxz = v.z;
#pragma unroll
    for (int off = 32; off >= 1; off >>= 1) {
        mnx = fminf(mnx, __shfl_xor(mnx, off, 64));
        mny = fminf(mny, __shfl_xor(mny, off, 64));
        mnz = fminf(mnz, __shfl_xor(mnz, off, 64));
        mxx = fmaxf(mxx, __shfl_xor(mxx, off, 64));
        mxy = fmaxf(mxy, __shfl_xor(mxy, off, 64));
        mxz = fmaxf(mxz, __shfl_xor(mxz, off, 64));
    }
    if (lane == 0) {
        bbmin[cw] = make_float4(mnx, mny, mnz, 0.f);
        bbmax[cw] = make_float4(mxx, mxy, mxz, 0.f);
    }
}

// sorted-ascending insert of one value (private, no cross-lane)
__device__ __forceinline__ void insert16(float (&keys)[KNN], float kk) {
#pragma unroll
    for (int s = KNN - 1; s >= 1; --s)
        keys[s] = __builtin_amdgcn_fmed3f(keys[s - 1], kk, keys[s]);
    keys[0] = fminf(keys[0], kk);
}

// Merge two ascending sorted-16 lists, keep lowest 16, result ascending.
// Symmetric in (a,o): both butterfly partners produce the identical result.
__device__ __forceinline__ void merge16(float (&a)[KNN], const float (&o)[KNN]) {
    float c[KNN];
#pragma unroll
    for (int s = 0; s < KNN; ++s) c[s] = fminf(a[s], o[KNN - 1 - s]);
#pragma unroll
    for (int st = KNN / 2; st >= 1; st >>= 1) {
#pragma unroll
        for (int base = 0; base < KNN; base += 2 * st) {
#pragma unroll
            for (int k = 0; k < st; ++k) {
                const float x = c[base + k], y = c[base + k + st];
                c[base + k]      = fminf(x, y);
                c[base + k + st] = fmaxf(x, y);
            }
        }
    }
#pragma unroll
    for (int s = 0; s < KNN; ++s) a[s] = c[s];
}

// ---- K1: 8-query/wave exact KNN + phi + first denoise (fused) ---------------
__global__ __launch_bounds__(256) void knn8_kernel(
        const float4* __restrict__ sorted4,
        const int*    __restrict__ perm,
        const float*  __restrict__ normals,
        const float4* __restrict__ bbmin,
        const float4* __restrict__ bbmax,
        int*   __restrict__ out_idx,      // sorted-local neighbor idx
        float* __restrict__ out_phi,
        float* __restrict__ out_n1) {     // sorted-order rows
    __shared__ float4 cb[4][2][64];       // per-wave double-buffered tile, 8KB

    const int tid  = threadIdx.x;
    const int lane = tid & 63;
    const int wv   = tid >> 6;
    const int W    = blockIdx.x * 4 + wv;        // 0..2047
    const int b    = W >> 10;                    // 1024 waves per batch
    const int qg   = W & 1023;
    const int qbase = qg * 8;                    // 8 consecutive sorted queries
    const int i    = lane & 7;                   // query within group
    const int u    = lane >> 3;                  // sub-lane (candidate stratum)
    const int qloc = qbase + i;                  // my query (sorted-local)
    const int c0   = qbase >> 6;                 // own chunk
    const float4* sb = sorted4 + (size_t)b * PP;

    const float4 q4 = sb[qloc];
    const float qx = q4.x, qy = q4.y, qz = q4.z;
    const float d2q = qx * qx + qy * qy + qz * qz;

    float keys[KNN];
#pragma unroll
    for (int s = 0; s < KNN; ++s) keys[s] = KEY_BIG;

    int par = 0;
    auto proc = [&](int c) {
        const float4 v4 = sb[c * 64 + lane];     // coalesced 1KB per wave
        cb[wv][par][lane] = v4;
#pragma unroll
        for (int t = 0; t < 8; ++t) {
            const float4 c4 = cb[wv][par][u + 8 * t];   // 8-way broadcast
            const int j = c * 64 + u + 8 * t;
            const float dot = fmaf(qz, c4.z, fmaf(qy, c4.y, qx * c4.x));
            const float d  = fmaf(-2.0f, dot, d2q + c4.w);
            const float dc = fmaxf(d, 0.0f);
            float kv = __uint_as_float(
                (__float_as_uint(dc) & 0xFFFFE000u) | (unsigned)j);
            if (j == qloc) kv = KEY_BIG;          // exclude self
            if (__any(kv < keys[KNN - 1])) insert16(keys, kv);
        }
        par ^= 1;
    };

    auto gated = [&](int c) {
        const float4 mn = bbmin[b * CH + c];      // wave-uniform -> s_load
        const float4 mx = bbmax[b * CH + c];
        const float ax = fmaxf(fmaxf(mn.x - qx, qx - mx.x), 0.0f);
        const float ay = fmaxf(fmaxf(mn.y - qy, qy - mx.y), 0.0f);
        const float az = fmaxf(fmaxf(mn.z - qz, qz - mx.z), 0.0f);
        const float dm = (ax * ax + ay * ay + az * az) * 0.999999f;
        const unsigned fl = __float_as_uint(dm) & 0xFFFFE000u;
        if (__any(fl < __float_as_uint(keys[KNN - 1]))) proc(c);
    };

    proc(c0);                                     // own chunk first, ungated
    for (int d = 1; d < CH; ++d) {                // near-first ring
        const int cp = c0 + d;
        if (cp < CH) gated(cp);
        const int cm = c0 - d;
        if (cm >= 0) gated(cm);
    }

    // ---- cross-lane: merge the 8 sub-lane lists per query (3 stages) ------
#pragma unroll
    for (int st = 0; st < 3; ++st) {
        const int S = 8 << st;
        float o[KNN];
#pragma unroll
        for (int s = 0; s < KNN; ++s) o[s] = __shfl_xor(keys[s], S, 64);
        merge16(keys, o);
    }
    // all 8 lanes of query i now hold the identical ascending final 16

    // ---- tail: lane (i,u) finalizes slots (2u, 2u+1) ----------------------
    const int sA = 2 * u, sB = 2 * u + 1;
    float kA = keys[0], kB = keys[0];
#pragma unroll
    for (int s = 1; s < KNN; ++s) {               // static-index extraction
        kA = (sA == s) ? keys[s] : kA;
        kB = (sB == s) ? keys[s] : kB;
    }
    const int jA = (int)(__float_as_uint(kA) & 0x1FFFu);
    const int jB = (int)(__float_as_uint(kB) & 0x1FFFu);

    const float4 a4 = sb[jA];
    const float4 b4 = sb[jB];
    const float dotA = fmaf(qz, a4.z, fmaf(qy, a4.y, qx * a4.x));
    const float dotB = fmaf(qz, b4.z, fmaf(qy, b4.y, qx * b4.x));
    float dA = fmaf(-2.0f, dotA, d2q + a4.w);
    float dB = fmaf(-2.0f, dotB, d2q + b4.w);
    dA = fmaxf(dA, 0.0f);
    dB = fmaxf(dB, 0.0f);

    float d1 = fminf(dA, dB);                     // min over 16 slots
#pragma unroll
    for (int st = 0; st < 3; ++st) d1 = fminf(d1, __shfl_xor(d1, 8 << st, 64));

    const float s0v  = d1 * 8.0f;                 // 2 * FILTER_SCALE^2 = 8
    const float sden = (s0v < EPSV) ? EPSV : s0v; // _eps_denom
    const float wA = fmaxf(1.0f - dA / sden, 0.0f);
    const float wB = fmaxf(1.0f - dB / sden, 0.0f);
    const float phA = (wA * wA) * (wA * wA);
    const float phB = (wB * wB) * (wB * wB);

    const int qrow = (b << 13) + qloc;            // sorted-order output row
    ((int2*)  out_idx)[qrow * 8 + u] = make_int2(jA, jB);
    ((float2*)out_phi)[qrow * 8 + u] = make_float2(phA, phB);

    // n1 partial (2 slots per lane), reduced across sub-lanes
    const float* bn = normals + (size_t)b * PP * 3;
    const int joA = perm[(b << 13) + jA];         // original idx (normals only)
    const int joB = perm[(b << 13) + jB];
    const float nax = bn[joA * 3 + 0], nay = bn[joA * 3 + 1], naz = bn[joA * 3 + 2];
    const float nbx = bn[joB * 3 + 0], nby = bn[joB * 3 + 1], nbz = bn[joB * 3 + 2];
    float px = phA * nax + phB * nbx;
    float py = phA * nay + phB * nby;
    float pz = phA * naz + phB * nbz;
    float ps = phA + phB;
#pragma unroll
    for (int st = 0; st < 3; ++st) {
        const int S = 8 << st;
        px += __shfl_xor(px, S, 64);
        py += __shfl_xor(py, S, 64);
        pz += __shfl_xor(pz, S, 64);
        ps += __shfl_xor(ps, S, 64);
    }
    if (u == 0) {
        const float den = (ps < EPSV) ? EPSV : ps;
        out_n1[qrow * 3 + 0] = px / den;
        out_n1[qrow * 3 + 1] = py / den;
        out_n1[qrow * 3 + 2] = pz / den;
    }
}

// ---- K2: normal_w + second denoise (n2), thread-per-(q,s), sorted space ----
__global__ __launch_bounds__(256) void denoise2_kernel(
        const int* __restrict__ idx,
        const float* __restrict__ phi,
        const float* __restrict__ n1,
        float* __restrict__ nw_out,
        float* __restrict__ n2_out) {
    const int gid = blockIdx.x * 256 + threadIdx.x;   // 0..262143
    const int q = gid >> 4;
    const int s = gid & 15;
    const int b = q >> 13;
    const int gbase = b * PP;
    const float INV_SIG = 1.0f / (0.75f * 0.75f);

    const float ax = n1[q * 3 + 0];                   // broadcast in 16-group
    const float ay = n1[q * 3 + 1];
    const float az = n1[q * 3 + 2];
    const float an = fmaxf(sqrtf(ax * ax + ay * ay + az * az), 1e-12f);
    const float rx = ax / an, ry = ay / an, rz = az / an;

    const int j = idx[q * KNN + s];                   // sorted-local
    const float bx = n1[(gbase + j) * 3 + 0];
    const float by = n1[(gbase + j) * 3 + 1];
    const float bz = n1[(gbase + j) * 3 + 2];
    const float bnn = fmaxf(sqrtf(bx * bx + by * by + bz * bz), 1e-12f);
    const float ux = bx / bnn - rx;
    const float uy = by / bnn - ry;
    const float uz = bz / bnn - rz;
    const float dq = ux * ux + uy * uy + uz * uz;
    const float nw = expf(-dq * INV_SIG);
    nw_out[q * KNN + s] = nw;

    const float wk = phi[q * KNN + s] * nw;
    float ox = wk * bx, oy = wk * by, oz = wk * bz, swn = wk;
#pragma unroll
    for (int off = 1; off < 16; off <<= 1) {
        ox  += __shfl_xor(ox,  off, 64);
        oy  += __shfl_xor(oy,  off, 64);
        oz  += __shfl_xor(oz,  off, 64);
        swn += __shfl_xor(swn, off, 64);
    }
    if (s == 0) {
        const float den = (swn < EPSV) ? EPSV : swn;
        n2_out[q * 3 + 0] = ox / den;
        n2_out[q * 3 + 1] = oy / den;
        n2_out[q * 3 + 2] = oz / den;
    }
}

// ---- K3: weights_proj + loss, thread-per-(q,s), sorted space ----------------
__global__ __launch_bounds__(256) void loss_kernel(
        const float4* __restrict__ sorted4,
        const int* __restrict__ idx,
        const float* __restrict__ phi,
        const float* __restrict__ nw,
        const float* __restrict__ n2,
        float* __restrict__ partial) {
    const int gid = blockIdx.x * 256 + threadIdx.x;   // 0..262143
    const int q = gid >> 4;
    const int s = gid & 15;
    const int b = q >> 13;
    const int il = q & (PP - 1);
    const float4* sbp = sorted4 + (size_t)b * PP;
    const int gbase = b * PP;

    const float4 p4 = sbp[il];                        // broadcast in 16-group
    const float px = p4.x, py = p4.y, pz = p4.z;
    const float d2q = px * px + py * py + pz * pz;

    const int j = idx[q * KNN + s];
    const float4 nb4 = sbp[j];
    const float dot = fmaf(pz, nb4.z, fmaf(py, nb4.y, px * nb4.x));
    const float dv  = fmaf(-2.0f, dot, d2q + nb4.w);
    const float d   = fmaxf(dv, 0.0f);                // bit-identical to knn8

    float d1 = d;
#pragma unroll
    for (int off = 1; off < 16; off <<= 1) d1 = fminf(d1, __shfl_xor(d1, off, 64));

    float w = phi[q * KNN + s] * nw[q * KNN + s];
    if (d > 4.0f * d1) w = 0.f;                       // ball-query mask

    const float nx = n2[(gbase + j) * 3 + 0];
    const float ny = n2[(gbase + j) * 3 + 1];
    const float nz = n2[(gbase + j) * 3 + 2];
    const float dts = (nb4.x - px) * nx +
                      (nb4.y - py) * ny +
                      (nb4.z - pz) * nz;
    float num = dts * dts * w, den = w;
#pragma unroll
    for (int off = 1; off < 16; off <<= 1) {
        num += __shfl_xor(num, off, 64);
        den += __shfl_xor(den, off, 64);
    }

    __shared__ float ls[16];
    if (s == 0) {
        const float dd = (den < EPSV) ? EPSV : den;
        ls[threadIdx.x >> 4] = num / dd;
    }
    __syncthreads();
    if (threadIdx.x == 0) {
        float v = 0.f;
#pragma unroll
        for (int k = 0; k < 16; ++k) v += ls[k];
        partial[blockIdx.x] = v;
    }
}

// ---- K4: final mean (1024 partials) ----------------------------------------
__global__ void finalize_kernel(const float* __restrict__ partial,
                                float* __restrict__ out) {
    float v = 0.f;
#pragma unroll
    for (int k = 0; k < 16; ++k) v += partial[threadIdx.x + 64 * k];
#pragma unroll
    for (int off = 32; off >= 1; off >>= 1) v += __shfl_down(v, off, 64);
    if (threadIdx.x == 0) out[0] = v / (float)NPTS;
}

// ---- launch -----------------------------------------------------------------
extern "C" void kernel_launch(void* const* d_in, const int* in_sizes, int n_in,
                              void* d_out, int out_size, void* d_ws, size_t ws_size,
                              hipStream_t stream) {
    const float* points  = (const float*)d_in[0];   // (2, 8192, 3) f32
    const float* normals = (const float*)d_in[1];   // (2, 8192, 3) f32
    float* out = (float*)d_out;                     // scalar f32

    // workspace layout (floats), total 951296 < proven 1147136 budget:
    //   idx   @ 0       (262144)
    //   phi   @ 262144  (262144)
    //   nw    @ 524288  (262144)  -- doubles as sort scratch (dead after knn)
    //   n1    @ 786432  (49152)
    //   n2    @ 835584  (49152)
    //   sorted4 @ 884736 (65536)  -- float4-aligned, live through loss
    //   part  @ 950272  (1024)
    float* wsf    = (float*)d_ws;
    int*   w_idx  = (int*)wsf;
    float* w_phi  = wsf + 262144;
    float* w_nw   = wsf + 524288;
    float* w_n1   = wsf + 786432;
    float* w_n2   = wsf + 835584;
    float4* w_sorted4 = (float4*)(wsf + 884736);
    float* w_part = wsf + 950272;
    // sort scratch inside the nw region (dead once knn8 completes)
    int*    w_perm   = (int*)(wsf + 524288);        // 16384 ints
    int*    w_hist   = (int*)(wsf + 540672);        // 8192 ints
    int*    w_cursor = (int*)(wsf + 548864);        // 8192 ints
    float4* w_bbmin  = (float4*)(wsf + 557056);     // 1024 floats
    float4* w_bbmax  = (float4*)(wsf + 558080);     // 1024 floats

    hipMemsetAsync(w_hist, 0, NB * NCELL * sizeof(int), stream);
    hist_kernel   <<<NPTS / 256, 256, 0, stream>>>(points, w_hist);
    scan_kernel   <<<NB, 1024, 0, stream>>>(w_hist, w_cursor);
    scatter_kernel<<<NPTS / 256, 256, 0, stream>>>(points, w_cursor, w_sorted4, w_perm);
    bbox_kernel   <<<32, 512, 0, stream>>>(w_sorted4, w_bbmin, w_bbmax);
    knn8_kernel   <<<512, 256, 0, stream>>>(w_sorted4, w_perm, normals,
                                            w_bbmin, w_bbmax,
                                            w_idx, w_phi, w_n1);
    denoise2_kernel<<<1024, 256, 0, stream>>>(w_idx, w_phi, w_n1, w_nw, w_n2);
    loss_kernel   <<<1024, 256, 0, stream>>>(w_sorted4, w_idx, w_phi, w_nw, w_n2, w_part);
    finalize_kernel<<<1, 64, 0, stream>>>(w_part, out);
}